// Round 3
// baseline (1083.814 us; speedup 1.0000x reference)
//
#include <hip/hip_runtime.h>
#include <math.h>

#define NW 5
#define NS 5
#define CDIM 640
#define HWDIM 1024
#define BDIM 25
constexpr int CHW = CDIM * HWDIM;                 // 655360
constexpr int NBIG = BDIM * CHW;                  // 16,384,000 elems
constexpr int WSZ = CDIM * CDIM;                  // 409,600
constexpr float QK_SCALE = 0.03952847075210474f;  // 1/sqrt(640)

typedef __attribute__((ext_vector_type(4))) float f32x4;
typedef __attribute__((ext_vector_type(8))) __bf16 bf16x8;
typedef __attribute__((ext_vector_type(4))) __bf16 bf16x4;
typedef __attribute__((ext_vector_type(2))) __bf16 bf16x2;

__device__ __forceinline__ void load_lds16(const __bf16* g, __bf16* l) {
    __builtin_amdgcn_global_load_lds(
        (const __attribute__((address_space(1))) void*)g,
        (__attribute__((address_space(3))) void*)l, 16, 0, 0);
}

// ---------------------------------------------------------------------------
// split fp32 -> (hi, lo) bf16, same layout. n4 = n/4.
// ---------------------------------------------------------------------------
__global__ __launch_bounds__(256) void split_f32(const float* __restrict__ s,
                                                 __bf16* __restrict__ dH,
                                                 __bf16* __restrict__ dL, int n4) {
    int i = blockIdx.x * 256 + threadIdx.x;
    if (i >= n4) return;
    f32x4 v = reinterpret_cast<const f32x4*>(s)[i];
    bf16x4 h, lo;
    #pragma unroll
    for (int q = 0; q < 4; ++q) {
        __bf16 hh = (__bf16)v[q];
        h[q] = hh;
        lo[q] = (__bf16)(v[q] - (float)hh);
    }
    reinterpret_cast<bf16x4*>(dH)[i] = h;
    reinterpret_cast<bf16x4*>(dL)[i] = lo;
}

// ---------------------------------------------------------------------------
// transpose [b][c][hw] fp32 -> [b][hw][c] (hi,lo) bf16. 32x32 tiles.
// grid (32, 20, 25), block 256.
// ---------------------------------------------------------------------------
__global__ __launch_bounds__(256) void tsplit(const float* __restrict__ x,
                                              __bf16* __restrict__ dH,
                                              __bf16* __restrict__ dL) {
    __shared__ float sT[32][33];
    const int hw0 = blockIdx.x * 32, c0 = blockIdx.y * 32, b = blockIdx.z;
    const int t = threadIdx.x;
    const int r = t >> 3, q4 = (t & 7) * 4;
    f32x4 v = *reinterpret_cast<const f32x4*>(
        &x[(size_t)b * CHW + (size_t)(c0 + r) * HWDIM + hw0 + q4]);
    #pragma unroll
    for (int i = 0; i < 4; ++i) sT[r][q4 + i] = v[i];
    __syncthreads();
    bf16x4 h, lo;
    #pragma unroll
    for (int i = 0; i < 4; ++i) {
        float xv = sT[q4 + i][r];
        __bf16 hh = (__bf16)xv;
        h[i] = hh;
        lo[i] = (__bf16)(xv - (float)hh);
    }
    size_t off = (size_t)b * CHW + (size_t)(hw0 + r) * CDIM + c0 + q4;
    *reinterpret_cast<bf16x4*>(&dH[off]) = h;
    *reinterpret_cast<bf16x4*>(&dL[off]) = lo;
}

// ===========================================================================
// Swizzled LDS tiles (T2, both-sides): tile = [128 rows][64 bf16] where
// logical cols 0-31 = hi, 32-63 = lo (128 B rows = 8 16B-chunks). Physical
// chunk = logical chunk ^ (row & 7). global_load_lds writes linearly, so the
// swizzle is applied via the per-lane GLOBAL source address (lane-constant
// lch = (l&7)^(l>>3)); reads use pchunk = cf ^ (fr&7). XOR is an involution,
// so both sides agree; each 16-lane read group covers all 8 bank slots 2x.
// ===========================================================================

// stage 128 rows x 32 c (hi+lo) into lds[128*64]; src pre-offset to tile row0.
__device__ __forceinline__ void stage_tile(const __bf16* __restrict__ srcH,
                                           const __bf16* __restrict__ srcL,
                                           __bf16* lds, int wv, int l, int c0) {
    const int lch = (l & 7) ^ (l >> 3);
    const int scol = (lch & 3) * 8;
    const int srw = l >> 3;
    const __bf16* src = (lch & 4) ? srcL : srcH;
    #pragma unroll
    for (int i = 0; i < 4; ++i) {
        const int r0 = wv * 32 + i * 8;
        load_lds16(&src[(size_t)(r0 + srw) * CDIM + c0 + scol], &lds[r0 * 64]);
    }
}

// ---------------------------------------------------------------------------
// conv1x1 via split-bf16 MFMA. in/out layout [b][hw][c]; W [o][c].
// grid (8 hw-tiles, 5 o-tiles, 25 b), block 256 (4 waves, 64o x 64hw each).
// ---------------------------------------------------------------------------
template <int RES>
__global__ __launch_bounds__(256) void conv_mfma(
    const __bf16* __restrict__ inH, const __bf16* __restrict__ inL,
    const __bf16* __restrict__ wH, const __bf16* __restrict__ wL,
    const float* __restrict__ bias,
    __bf16* __restrict__ outH, __bf16* __restrict__ outL) {
    __shared__ __bf16 sA[128 * 64];  // weights [o][hi|lo]
    __shared__ __bf16 sB[128 * 64];  // input   [hw][hi|lo]
    const int hw0 = blockIdx.x * 128;
    const int o0 = blockIdx.y * 128;
    const int b = blockIdx.z;
    const int tid = threadIdx.x;
    const int wv = tid >> 6, l = tid & 63;
    const int wo = (wv >> 1) * 64, wh = (wv & 1) * 64;
    const size_t inBase = (size_t)b * CHW;

    const __bf16* wSrcH = wH + (size_t)o0 * CDIM;
    const __bf16* wSrcL = wL + (size_t)o0 * CDIM;
    const __bf16* iSrcH = inH + inBase + (size_t)hw0 * CDIM;
    const __bf16* iSrcL = inL + inBase + (size_t)hw0 * CDIM;

    f32x4 acc[4][4];
    #pragma unroll
    for (int i = 0; i < 4; ++i)
        #pragma unroll
        for (int j = 0; j < 4; ++j) acc[i][j] = (f32x4){0.f, 0.f, 0.f, 0.f};

    const int fr = l & 15, cf = l >> 4;
    const int ehi = (cf ^ (fr & 7)) * 8;  // element offset of hi chunk in row

    for (int c0 = 0; c0 < CDIM; c0 += 32) {
        stage_tile(wSrcH, wSrcL, sA, wv, l, c0);
        stage_tile(iSrcH, iSrcL, sB, wv, l, c0);
        __syncthreads();
        bf16x8 aH[4], aL[4], bH[4], bL[4];
        #pragma unroll
        for (int i = 0; i < 4; ++i) {
            const int ra = (wo + i * 16 + fr) * 64;
            const int rb = (wh + i * 16 + fr) * 64;
            aH[i] = *reinterpret_cast<const bf16x8*>(&sA[ra + ehi]);
            aL[i] = *reinterpret_cast<const bf16x8*>(&sA[ra + (ehi ^ 32)]);
            bH[i] = *reinterpret_cast<const bf16x8*>(&sB[rb + ehi]);
            bL[i] = *reinterpret_cast<const bf16x8*>(&sB[rb + (ehi ^ 32)]);
        }
        #pragma unroll
        for (int i = 0; i < 4; ++i)
            #pragma unroll
            for (int j = 0; j < 4; ++j) {
                acc[i][j] = __builtin_amdgcn_mfma_f32_16x16x32_bf16(
                    aH[i], bH[j], acc[i][j], 0, 0, 0);
                acc[i][j] = __builtin_amdgcn_mfma_f32_16x16x32_bf16(
                    aH[i], bL[j], acc[i][j], 0, 0, 0);
                acc[i][j] = __builtin_amdgcn_mfma_f32_16x16x32_bf16(
                    aL[i], bH[j], acc[i][j], 0, 0, 0);
            }
        __syncthreads();
    }

    const int og = (l >> 4) * 4;  // 4 consecutive o per lane
    const int cl = l & 15;        // hw within fragment
    #pragma unroll
    for (int i = 0; i < 4; ++i) {
        const int o = o0 + wo + i * 16 + og;
        const f32x4 bs = *reinterpret_cast<const f32x4*>(&bias[o]);
        #pragma unroll
        for (int j = 0; j < 4; ++j) {
            const int hw = hw0 + wh + j * 16 + cl;
            const size_t off = inBase + (size_t)hw * CDIM + o;
            float r[4];
            #pragma unroll
            for (int q = 0; q < 4; ++q) r[q] = acc[i][j][q] + bs[q];
            if (RES) {
                bf16x4 rh = *reinterpret_cast<const bf16x4*>(&inH[off]);
                bf16x4 rl = *reinterpret_cast<const bf16x4*>(&inL[off]);
                #pragma unroll
                for (int q = 0; q < 4; ++q) r[q] += (float)rh[q] + (float)rl[q];
            }
            bf16x4 oh, ol;
            #pragma unroll
            for (int q = 0; q < 4; ++q) {
                __bf16 hh = (__bf16)r[q];
                oh[q] = hh;
                ol[q] = (__bf16)(r[q] - (float)hh);
            }
            *reinterpret_cast<bf16x4*>(&outH[off]) = oh;
            *reinterpret_cast<bf16x4*>(&outL[off]) = ol;
        }
    }
}

// ---------------------------------------------------------------------------
// attention scores fused with per-key spatial max, split-bf16 MFMA.
// gpart[(w,ks), sq*1024+q] = scale * max_k sum_c Q[(w,sq),q,c]*K[(w,ks),k,c]
// grid (40 q-tiles, 5 ks, 5 w), block 256 (4 waves, tile 128q x 128k).
// ---------------------------------------------------------------------------
__global__ __launch_bounds__(256) void attn_mfma(
    const __bf16* __restrict__ qH, const __bf16* __restrict__ qL,
    const __bf16* __restrict__ kH, const __bf16* __restrict__ kL,
    float* __restrict__ gpart) {
    __shared__ __bf16 sQ[128 * 64];
    __shared__ __bf16 sK[128 * 64];
    __shared__ float sRed[2][128];
    const int qt = blockIdx.x;  // 0..39
    const int ks = blockIdx.y, wy = blockIdx.z;
    const int sq = qt >> 3, q0 = (qt & 7) * 128;
    const int tid = threadIdx.x;
    const int wv = tid >> 6, l = tid & 63;
    const int wq = (wv >> 1) * 64;
    const int kh = wv & 1;
    const int wk = kh * 64;
    const __bf16* qSrcH = qH + (size_t)(wy * NS + sq) * CHW + (size_t)q0 * CDIM;
    const __bf16* qSrcL = qL + (size_t)(wy * NS + sq) * CHW + (size_t)q0 * CDIM;
    const __bf16* kBaseH = kH + (size_t)(wy * NS + ks) * CHW;
    const __bf16* kBaseL = kL + (size_t)(wy * NS + ks) * CHW;

    float qmax[4][4];
    #pragma unroll
    for (int i = 0; i < 4; ++i)
        #pragma unroll
        for (int q = 0; q < 4; ++q) qmax[i][q] = -INFINITY;

    const int fr = l & 15, cf = l >> 4;
    const int ehi = (cf ^ (fr & 7)) * 8;

    for (int kc = 0; kc < HWDIM; kc += 128) {
        const __bf16* kSrcH = kBaseH + (size_t)kc * CDIM;
        const __bf16* kSrcL = kBaseL + (size_t)kc * CDIM;
        f32x4 acc[4][4];
        #pragma unroll
        for (int i = 0; i < 4; ++i)
            #pragma unroll
            for (int j = 0; j < 4; ++j) acc[i][j] = (f32x4){0.f, 0.f, 0.f, 0.f};

        for (int c0 = 0; c0 < CDIM; c0 += 32) {
            stage_tile(qSrcH, qSrcL, sQ, wv, l, c0);
            stage_tile(kSrcH, kSrcL, sK, wv, l, c0);
            __syncthreads();
            bf16x8 aH[4], aL[4], bH[4], bL[4];
            #pragma unroll
            for (int i = 0; i < 4; ++i) {
                const int ra = (wq + i * 16 + fr) * 64;
                const int rb = (wk + i * 16 + fr) * 64;
                aH[i] = *reinterpret_cast<const bf16x8*>(&sQ[ra + ehi]);
                aL[i] = *reinterpret_cast<const bf16x8*>(&sQ[ra + (ehi ^ 32)]);
                bH[i] = *reinterpret_cast<const bf16x8*>(&sK[rb + ehi]);
                bL[i] = *reinterpret_cast<const bf16x8*>(&sK[rb + (ehi ^ 32)]);
            }
            __builtin_amdgcn_s_setprio(1);
            #pragma unroll
            for (int i = 0; i < 4; ++i)
                #pragma unroll
                for (int j = 0; j < 4; ++j) {
                    acc[i][j] = __builtin_amdgcn_mfma_f32_16x16x32_bf16(
                        aH[i], bH[j], acc[i][j], 0, 0, 0);
                    acc[i][j] = __builtin_amdgcn_mfma_f32_16x16x32_bf16(
                        aH[i], bL[j], acc[i][j], 0, 0, 0);
                    acc[i][j] = __builtin_amdgcn_mfma_f32_16x16x32_bf16(
                        aL[i], bH[j], acc[i][j], 0, 0, 0);
                }
            __builtin_amdgcn_s_setprio(0);
            __syncthreads();
        }
        #pragma unroll
        for (int i = 0; i < 4; ++i)
            #pragma unroll
            for (int q = 0; q < 4; ++q) {
                float m = fmaxf(fmaxf(acc[i][0][q], acc[i][1][q]),
                                fmaxf(acc[i][2][q], acc[i][3][q]));
                qmax[i][q] = fmaxf(qmax[i][q], m);
            }
    }
    // reduce max over k (lane groups of 16 share q rows)
    #pragma unroll
    for (int i = 0; i < 4; ++i)
        #pragma unroll
        for (int q = 0; q < 4; ++q) {
            float v = qmax[i][q];
            v = fmaxf(v, __shfl_xor(v, 1));
            v = fmaxf(v, __shfl_xor(v, 2));
            v = fmaxf(v, __shfl_xor(v, 4));
            v = fmaxf(v, __shfl_xor(v, 8));
            qmax[i][q] = v;
        }
    if ((l & 15) == 0) {
        const int g = l >> 4;
        #pragma unroll
        for (int i = 0; i < 4; ++i)
            #pragma unroll
            for (int q = 0; q < 4; ++q)
                sRed[kh][wq + i * 16 + g * 4 + q] = qmax[i][q];
    }
    __syncthreads();
    if (tid < 128) {
        float m = fmaxf(sRed[0][tid], sRed[1][tid]);
        gpart[(size_t)(wy * NS + ks) * (NS * HWDIM) + sq * HWDIM + q0 + tid] =
            m * QK_SCALE;
    }
}

// ---------------------------------------------------------------------------
// mean over key shots -> softmax over hw per (way, sq) -> argmax mask indices
// grid 25 = (w, sq), block 256 (4 hw each).
// ---------------------------------------------------------------------------
__global__ __launch_bounds__(256) void softmax_mask(const float* __restrict__ gpart,
                                                    int* __restrict__ gIdx,
                                                    int* __restrict__ gCnt) {
    const int bb = blockIdx.x;
    const int w = bb / NS, sq = bb % NS;
    const int tid = threadIdx.x;
    __shared__ float sred[256];
    __shared__ int sCnt;

    float v[4];
    #pragma unroll
    for (int i = 0; i < 4; ++i) {
        int hw = tid + 256 * i;
        float s = 0.f;
        #pragma unroll
        for (int ks = 0; ks < NS; ++ks)
            s += gpart[(size_t)(w * NS + ks) * (NS * HWDIM) + sq * HWDIM + hw];
        v[i] = s * 0.2f;
    }
    float m = fmaxf(fmaxf(v[0], v[1]), fmaxf(v[2], v[3]));
    sred[tid] = m;
    __syncthreads();
    for (int s = 128; s > 0; s >>= 1) {
        if (tid < s) sred[tid] = fmaxf(sred[tid], sred[tid + s]);
        __syncthreads();
    }
    float rowmax = sred[0];
    __syncthreads();
    float e[4], ls = 0.f;
    #pragma unroll
    for (int i = 0; i < 4; ++i) { e[i] = expf(v[i] - rowmax); ls += e[i]; }
    sred[tid] = ls;
    __syncthreads();
    for (int s = 128; s > 0; s >>= 1) {
        if (tid < s) sred[tid] += sred[tid + s];
        __syncthreads();
    }
    float ssum = sred[0];
    __syncthreads();
    float p[4], pm = 0.f;
    #pragma unroll
    for (int i = 0; i < 4; ++i) { p[i] = e[i] / ssum; pm = fmaxf(pm, p[i]); }
    sred[tid] = pm;
    __syncthreads();
    for (int s = 128; s > 0; s >>= 1) {
        if (tid < s) sred[tid] = fmaxf(sred[tid], sred[tid + s]);
        __syncthreads();
    }
    float pmax = sred[0];
    if (tid == 0) sCnt = 0;
    __syncthreads();
    #pragma unroll
    for (int i = 0; i < 4; ++i) {
        if (p[i] == pmax) {
            int slot = atomicAdd(&sCnt, 1);
            gIdx[bb * HWDIM + slot] = tid + 256 * i;
        }
    }
    __syncthreads();
    if (tid == 0) gCnt[bb] = sCnt;
}

// ---------------------------------------------------------------------------
// inv_nrm per (bb,hw) row: 1/max(sqrt(sum_c y^2), eps). y = hi+lo, [bb][hw][c].
// grid 1600 (16 rows/block), block 256 (16 lanes per row).
// ---------------------------------------------------------------------------
__global__ __launch_bounds__(256) void nrm_k(const __bf16* __restrict__ yH,
                                             const __bf16* __restrict__ yL,
                                             float* __restrict__ inv) {
    const int row = blockIdx.x * 16 + (threadIdx.x >> 4);
    const int cq = threadIdx.x & 15;
    const size_t base = (size_t)row * CDIM;
    float s = 0.f;
    #pragma unroll
    for (int i = 0; i < 10; ++i) {
        int c = i * 64 + cq * 4;
        bf16x4 h = *reinterpret_cast<const bf16x4*>(&yH[base + c]);
        bf16x4 lo = *reinterpret_cast<const bf16x4*>(&yL[base + c]);
        #pragma unroll
        for (int q = 0; q < 4; ++q) {
            float x = (float)h[q] + (float)lo[q];
            s = fmaf(x, x, s);
        }
    }
    s += __shfl_xor(s, 1);
    s += __shfl_xor(s, 2);
    s += __shfl_xor(s, 4);
    s += __shfl_xor(s, 8);
    if (cq == 0) inv[row] = 1.0f / fmaxf(sqrtf(s), 1e-12f);
}

// ---------------------------------------------------------------------------
// seeds[bb,c] = sum over masked hw of y[bb,hw,c]*inv[bb,hw]
// grid 25, block 640.
// ---------------------------------------------------------------------------
__global__ __launch_bounds__(640) void seeds_k(const __bf16* __restrict__ yH,
                                               const __bf16* __restrict__ yL,
                                               const float* __restrict__ inv,
                                               const int* __restrict__ gIdx,
                                               const int* __restrict__ gCnt,
                                               float* __restrict__ seeds) {
    const int bb = blockIdx.x, c = threadIdx.x;
    const int cnt = gCnt[bb];
    float s = 0.f;
    for (int e = 0; e < cnt; ++e) {
        int hw = gIdx[bb * HWDIM + e];
        size_t off = (size_t)bb * CHW + (size_t)hw * CDIM + c;
        s += ((float)yH[off] + (float)yL[off]) * inv[bb * HWDIM + hw];
    }
    seeds[bb * CDIM + c] = s;
}

// ---------------------------------------------------------------------------
// cm[way,o,hw] = sum_k inv[(way,k),hw] * sum_c y[(way,k),hw,c]*seeds[o*5+k,c]
// grid (256, 5), block 256 (wave per hw row).
// ---------------------------------------------------------------------------
__global__ __launch_bounds__(256) void cm_k(const __bf16* __restrict__ yH,
                                            const __bf16* __restrict__ yL,
                                            const float* __restrict__ inv,
                                            const float* __restrict__ seeds,
                                            float* __restrict__ cm) {
    __shared__ float sS[BDIM * CDIM];  // 64000 B
    const int way = blockIdx.y;
    const int tid = threadIdx.x, wv = tid >> 6, l = tid & 63;
    const int hw = blockIdx.x * 4 + wv;
    for (int e = tid; e < BDIM * CDIM; e += 256) sS[e] = seeds[e];
    __syncthreads();
    float acc[NW] = {0.f, 0.f, 0.f, 0.f, 0.f};
    for (int k = 0; k < NS; ++k) {
        const size_t base = (size_t)(way * NS + k) * CHW + (size_t)hw * CDIM;
        float t[NW] = {0.f, 0.f, 0.f, 0.f, 0.f};
        #pragma unroll
        for (int i = 0; i < 5; ++i) {
            int c = (i * 64 + l) * 2;
            bf16x2 h = *reinterpret_cast<const bf16x2*>(&yH[base + c]);
            bf16x2 lo = *reinterpret_cast<const bf16x2*>(&yL[base + c]);
            float x0 = (float)h[0] + (float)lo[0];
            float x1 = (float)h[1] + (float)lo[1];
            #pragma unroll
            for (int o = 0; o < NW; ++o) {
                t[o] = fmaf(x0, sS[(o * NS + k) * CDIM + c], t[o]);
                t[o] = fmaf(x1, sS[(o * NS + k) * CDIM + c + 1], t[o]);
            }
        }
        float iv = inv[(way * NS + k) * HWDIM + hw];
        #pragma unroll
        for (int o = 0; o < NW; ++o) acc[o] = fmaf(t[o], iv, acc[o]);
    }
    #pragma unroll
    for (int o = 0; o < NW; ++o) {
        float v = acc[o];
        v += __shfl_xor(v, 1);
        v += __shfl_xor(v, 2);
        v += __shfl_xor(v, 4);
        v += __shfl_xor(v, 8);
        v += __shfl_xor(v, 16);
        v += __shfl_xor(v, 32);
        if (l == 0) cm[(size_t)(way * NW + o) * HWDIM + hw] = v;
    }
}

// ---------------------------------------------------------------------------
// in-place min-max normalize each row of 1024. grid 25, block 256.
// ---------------------------------------------------------------------------
__global__ __launch_bounds__(256) void minmax_kernel(float* __restrict__ cm) {
    const int row = blockIdx.x;
    const int tid = threadIdx.x;
    __shared__ float smn[256], smx[256];
    float v[4];
    #pragma unroll
    for (int i = 0; i < 4; ++i) v[i] = cm[(size_t)row * HWDIM + tid + 256 * i];
    float mn = fminf(fminf(v[0], v[1]), fminf(v[2], v[3]));
    float mx = fmaxf(fmaxf(v[0], v[1]), fmaxf(v[2], v[3]));
    smn[tid] = mn;
    smx[tid] = mx;
    __syncthreads();
    for (int s = 128; s > 0; s >>= 1) {
        if (tid < s) {
            smn[tid] = fminf(smn[tid], smn[tid + s]);
            smx[tid] = fmaxf(smx[tid], smx[tid + s]);
        }
        __syncthreads();
    }
    float cmin = smn[0], cmax = smx[0];
    float den = cmax - cmin + 1e-12f;
    #pragma unroll
    for (int i = 0; i < 4; ++i)
        cm[(size_t)row * HWDIM + tid + 256 * i] = (v[i] - cmin) / den;
}

// ---------------------------------------------------------------------------
// proto partials + reduce.
// ---------------------------------------------------------------------------
__global__ __launch_bounds__(128) void proto_part_k(const __bf16* __restrict__ yH,
                                                    const __bf16* __restrict__ yL,
                                                    const float* __restrict__ cmn,
                                                    float* __restrict__ part) {
    const int w = blockIdx.x, cc = blockIdx.y, hs = blockIdx.z;
    const int c = cc * 128 + threadIdx.x;
    float s = 0.f;
    for (int i = 0; i < 640; ++i) {
        int g = hs * 640 + i, sh = g >> 10, hw = g & 1023;
        size_t off = (size_t)(w * NS + sh) * CHW + (size_t)hw * CDIM + c;
        s = fmaf((float)yH[off] + (float)yL[off],
                 cmn[(w * NS + sh) * HWDIM + hw], s);
    }
    part[((w * 5 + cc) * 8 + hs) * 128 + threadIdx.x] = s;
}

__global__ __launch_bounds__(128) void proto_red_k(const float* __restrict__ part,
                                                   float* __restrict__ out) {
    const int bid = blockIdx.x;  // w*5+cc
    float s = 0.f;
    #pragma unroll
    for (int hs = 0; hs < 8; ++hs) s += part[(bid * 8 + hs) * 128 + threadIdx.x];
    const int w = bid / 5, cc = bid % 5;
    out[w * CDIM + cc * 128 + threadIdx.x] = s * (1.0f / 5120.0f);
}

// ---------------------------------------------------------------------------
extern "C" void kernel_launch(void* const* d_in, const int* in_sizes, int n_in,
                              void* d_out, int out_size, void* d_ws, size_t ws_size,
                              hipStream_t stream) {
    const float* x5 = (const float*)d_in[0];
    const float* Wc = (const float*)d_in[1];
    const float* bc = (const float*)d_in[2];
    const float* Wq = (const float*)d_in[3];
    const float* bq = (const float*)d_in[4];
    const float* Wk = (const float*)d_in[5];
    const float* bk = (const float*)d_in[6];
    float* out = (float*)d_out;

    __bf16* big = (__bf16*)d_ws;
    __bf16* A_hi = big;
    __bf16* A_lo = big + (size_t)NBIG;
    __bf16* B_hi = big + (size_t)2 * NBIG;
    __bf16* B_lo = big + (size_t)3 * NBIG;
    __bf16* C_hi = big + (size_t)4 * NBIG;
    __bf16* C_lo = big + (size_t)5 * NBIG;
    __bf16* wp = big + (size_t)6 * NBIG;
    __bf16* WcH = wp;
    __bf16* WcL = wp + WSZ;
    __bf16* WqH = wp + 2 * WSZ;
    __bf16* WqL = wp + 3 * WSZ;
    __bf16* WkH = wp + 4 * WSZ;
    __bf16* WkL = wp + 5 * WSZ;
    float* fp = (float*)(wp + 6 * WSZ);
    float* gpart = fp;                    // 128000
    float* invb = fp + 128000;            // 25600
    float* seedsb = fp + 153600;          // 16000
    float* cmb = fp + 169600;             // 25600
    float* partb = fp + 195200;           // 25600
    int* gIdx = (int*)(fp + 220800);      // 25600
    int* gCnt = gIdx + BDIM * HWDIM;      // 25

    const int W4 = WSZ / 4;
    split_f32<<<dim3((W4 + 255) / 256), 256, 0, stream>>>(Wc, WcH, WcL, W4);
    split_f32<<<dim3((W4 + 255) / 256), 256, 0, stream>>>(Wq, WqH, WqL, W4);
    split_f32<<<dim3((W4 + 255) / 256), 256, 0, stream>>>(Wk, WkH, WkL, W4);
    tsplit<<<dim3(32, 20, 25), 256, 0, stream>>>(x5, A_hi, A_lo);

    dim3 gG(8, 5, 25);
    // y1 = conv(x,Wc)+x
    conv_mfma<1><<<gG, 256, 0, stream>>>(A_hi, A_lo, WcH, WcL, bc, B_hi, B_lo);
    // y2 = conv(y1,Wq)
    conv_mfma<0><<<gG, 256, 0, stream>>>(B_hi, B_lo, WqH, WqL, bq, C_hi, C_lo);
    // xq = conv(y2,Wq)  (into B, y1 dead)
    conv_mfma<0><<<gG, 256, 0, stream>>>(C_hi, C_lo, WqH, WqL, bq, B_hi, B_lo);
    // xk = conv(y2,Wk)  (into A, x dead)
    conv_mfma<0><<<gG, 256, 0, stream>>>(C_hi, C_lo, WkH, WkL, bk, A_hi, A_lo);

    attn_mfma<<<dim3(40, 5, 5), 256, 0, stream>>>(B_hi, B_lo, A_hi, A_lo, gpart);
    softmax_mask<<<25, 256, 0, stream>>>(gpart, gIdx, gCnt);
    nrm_k<<<1600, 256, 0, stream>>>(C_hi, C_lo, invb);
    seeds_k<<<25, 640, 0, stream>>>(C_hi, C_lo, invb, gIdx, gCnt, seedsb);
    cm_k<<<dim3(256, 5), 256, 0, stream>>>(C_hi, C_lo, invb, seedsb, cmb);
    minmax_kernel<<<25, 256, 0, stream>>>(cmb);
    proto_part_k<<<dim3(5, 5, 8), 128, 0, stream>>>(C_hi, C_lo, cmb, partb);
    proto_red_k<<<25, 128, 0, stream>>>(partb, out);
}

// Round 4
// 1082.110 us; speedup vs baseline: 1.0016x; 1.0016x over previous
//
#include <hip/hip_runtime.h>
#include <math.h>

#define NW 5
#define NS 5
#define CDIM 640
#define HWDIM 1024
#define BDIM 25
constexpr int CHW = CDIM * HWDIM;                 // 655360
constexpr int NBIG = BDIM * CHW;                  // 16,384,000 elems
constexpr int WSZ = CDIM * CDIM;                  // 409,600
constexpr float QK_SCALE = 0.03952847075210474f;  // 1/sqrt(640)

typedef __attribute__((ext_vector_type(4))) float f32x4;
typedef __attribute__((ext_vector_type(8))) __bf16 bf16x8;
typedef __attribute__((ext_vector_type(4))) __bf16 bf16x4;
typedef __attribute__((ext_vector_type(2))) __bf16 bf16x2;

__device__ __forceinline__ void load_lds16(const __bf16* g, __bf16* l) {
    __builtin_amdgcn_global_load_lds(
        (const __attribute__((address_space(1))) void*)g,
        (__attribute__((address_space(3))) void*)l, 16, 0, 0);
}

// ---------------------------------------------------------------------------
// split fp32 -> (hi, lo) bf16, same layout. n4 = n/4.
// ---------------------------------------------------------------------------
__global__ __launch_bounds__(256) void split_f32(const float* __restrict__ s,
                                                 __bf16* __restrict__ dH,
                                                 __bf16* __restrict__ dL, int n4) {
    int i = blockIdx.x * 256 + threadIdx.x;
    if (i >= n4) return;
    f32x4 v = reinterpret_cast<const f32x4*>(s)[i];
    bf16x4 h, lo;
    #pragma unroll
    for (int q = 0; q < 4; ++q) {
        __bf16 hh = (__bf16)v[q];
        h[q] = hh;
        lo[q] = (__bf16)(v[q] - (float)hh);
    }
    reinterpret_cast<bf16x4*>(dH)[i] = h;
    reinterpret_cast<bf16x4*>(dL)[i] = lo;
}

// ---------------------------------------------------------------------------
// transpose [b][c][hw] fp32 -> [b][hw][c] (hi,lo) bf16. 32x32 tiles.
// grid (32, 20, 25), block 256.
// ---------------------------------------------------------------------------
__global__ __launch_bounds__(256) void tsplit(const float* __restrict__ x,
                                              __bf16* __restrict__ dH,
                                              __bf16* __restrict__ dL) {
    __shared__ float sT[32][33];
    const int hw0 = blockIdx.x * 32, c0 = blockIdx.y * 32, b = blockIdx.z;
    const int t = threadIdx.x;
    const int r = t >> 3, q4 = (t & 7) * 4;
    f32x4 v = *reinterpret_cast<const f32x4*>(
        &x[(size_t)b * CHW + (size_t)(c0 + r) * HWDIM + hw0 + q4]);
    #pragma unroll
    for (int i = 0; i < 4; ++i) sT[r][q4 + i] = v[i];
    __syncthreads();
    bf16x4 h, lo;
    #pragma unroll
    for (int i = 0; i < 4; ++i) {
        float xv = sT[q4 + i][r];
        __bf16 hh = (__bf16)xv;
        h[i] = hh;
        lo[i] = (__bf16)(xv - (float)hh);
    }
    size_t off = (size_t)b * CHW + (size_t)(hw0 + r) * CDIM + c0 + q4;
    *reinterpret_cast<bf16x4*>(&dH[off]) = h;
    *reinterpret_cast<bf16x4*>(&dL[off]) = lo;
}

// ===========================================================================
// Swizzled LDS tiles (T2, both-sides): tile = [128 rows][64 bf16], logical
// cols 0-31 = hi, 32-63 = lo. Physical 16B-chunk = logical chunk ^ (row&7),
// applied on the global source address at stage time (lane-constant) and on
// the ds_read offset (ehi) at read time. XOR is an involution -> consistent.
// ===========================================================================
__device__ __forceinline__ void stage_tile(const __bf16* __restrict__ srcH,
                                           const __bf16* __restrict__ srcL,
                                           __bf16* lds, int wv, int l, int c0) {
    const int lch = (l & 7) ^ (l >> 3);
    const int scol = (lch & 3) * 8;
    const int srw = l >> 3;
    const __bf16* src = (lch & 4) ? srcL : srcH;
    #pragma unroll
    for (int i = 0; i < 4; ++i) {
        const int r0 = wv * 32 + i * 8;
        load_lds16(&src[(size_t)(r0 + srw) * CDIM + c0 + scol], &lds[r0 * 64]);
    }
}

// ---------------------------------------------------------------------------
// conv1x1 via split-bf16 MFMA, 2-phase pipelined (m248 recipe):
// dbuf LDS; issue STAGE(t+1) BEFORE compute(t); ONE __syncthreads per step.
// grid (8 hw-tiles, 5 o-tiles, 25 b), block 256 (4 waves, 64o x 64hw each).
// ---------------------------------------------------------------------------
template <int RES>
__global__ __launch_bounds__(256) void conv_mfma(
    const __bf16* __restrict__ inH, const __bf16* __restrict__ inL,
    const __bf16* __restrict__ wH, const __bf16* __restrict__ wL,
    const float* __restrict__ bias,
    __bf16* __restrict__ outH, __bf16* __restrict__ outL) {
    __shared__ __bf16 sA[2][128 * 64];  // weights [o][hi|lo]
    __shared__ __bf16 sB[2][128 * 64];  // input   [hw][hi|lo]
    const int hw0 = blockIdx.x * 128;
    const int o0 = blockIdx.y * 128;
    const int b = blockIdx.z;
    const int tid = threadIdx.x;
    const int wv = tid >> 6, l = tid & 63;
    const int wo = (wv >> 1) * 64, wh = (wv & 1) * 64;
    const size_t inBase = (size_t)b * CHW;

    const __bf16* wSrcH = wH + (size_t)o0 * CDIM;
    const __bf16* wSrcL = wL + (size_t)o0 * CDIM;
    const __bf16* iSrcH = inH + inBase + (size_t)hw0 * CDIM;
    const __bf16* iSrcL = inL + inBase + (size_t)hw0 * CDIM;

    f32x4 acc[4][4];
    #pragma unroll
    for (int i = 0; i < 4; ++i)
        #pragma unroll
        for (int j = 0; j < 4; ++j) acc[i][j] = (f32x4){0.f, 0.f, 0.f, 0.f};

    const int fr = l & 15, cf = l >> 4;
    const int ehi = (cf ^ (fr & 7)) * 8;  // element offset of hi chunk in row

    // prologue: stage step 0 into buf 0
    stage_tile(wSrcH, wSrcL, sA[0], wv, l, 0);
    stage_tile(iSrcH, iSrcL, sB[0], wv, l, 0);
    __syncthreads();

    constexpr int NT = CDIM / 32;  // 20
    for (int t = 0; t < NT; ++t) {
        const int cur = t & 1;
        if (t + 1 < NT) {
            stage_tile(wSrcH, wSrcL, sA[cur ^ 1], wv, l, (t + 1) * 32);
            stage_tile(iSrcH, iSrcL, sB[cur ^ 1], wv, l, (t + 1) * 32);
        }
        bf16x8 aH[4], aL[4], bH[4], bL[4];
        #pragma unroll
        for (int i = 0; i < 4; ++i) {
            const int ra = (wo + i * 16 + fr) * 64;
            const int rb = (wh + i * 16 + fr) * 64;
            aH[i] = *reinterpret_cast<const bf16x8*>(&sA[cur][ra + ehi]);
            aL[i] = *reinterpret_cast<const bf16x8*>(&sA[cur][ra + (ehi ^ 32)]);
            bH[i] = *reinterpret_cast<const bf16x8*>(&sB[cur][rb + ehi]);
            bL[i] = *reinterpret_cast<const bf16x8*>(&sB[cur][rb + (ehi ^ 32)]);
        }
        #pragma unroll
        for (int i = 0; i < 4; ++i)
            #pragma unroll
            for (int j = 0; j < 4; ++j) {
                acc[i][j] = __builtin_amdgcn_mfma_f32_16x16x32_bf16(
                    aH[i], bH[j], acc[i][j], 0, 0, 0);
                acc[i][j] = __builtin_amdgcn_mfma_f32_16x16x32_bf16(
                    aH[i], bL[j], acc[i][j], 0, 0, 0);
                acc[i][j] = __builtin_amdgcn_mfma_f32_16x16x32_bf16(
                    aL[i], bH[j], acc[i][j], 0, 0, 0);
            }
        __syncthreads();  // drains vmcnt (next-tile loads) + protects dbuf flip
    }

    const int og = (l >> 4) * 4;  // 4 consecutive o per lane
    const int cl = l & 15;        // hw within fragment
    #pragma unroll
    for (int i = 0; i < 4; ++i) {
        const int o = o0 + wo + i * 16 + og;
        const f32x4 bs = *reinterpret_cast<const f32x4*>(&bias[o]);
        #pragma unroll
        for (int j = 0; j < 4; ++j) {
            const int hw = hw0 + wh + j * 16 + cl;
            const size_t off = inBase + (size_t)hw * CDIM + o;
            float r[4];
            #pragma unroll
            for (int q = 0; q < 4; ++q) r[q] = acc[i][j][q] + bs[q];
            if (RES) {
                bf16x4 rh = *reinterpret_cast<const bf16x4*>(&inH[off]);
                bf16x4 rl = *reinterpret_cast<const bf16x4*>(&inL[off]);
                #pragma unroll
                for (int q = 0; q < 4; ++q) r[q] += (float)rh[q] + (float)rl[q];
            }
            bf16x4 oh, ol;
            #pragma unroll
            for (int q = 0; q < 4; ++q) {
                __bf16 hh = (__bf16)r[q];
                oh[q] = hh;
                ol[q] = (__bf16)(r[q] - (float)hh);
            }
            *reinterpret_cast<bf16x4*>(&outH[off]) = oh;
            *reinterpret_cast<bf16x4*>(&outL[off]) = ol;
        }
    }
}

// ---------------------------------------------------------------------------
// attention scores fused with per-key spatial max, split-bf16 MFMA,
// 2-phase pipelined across the flattened (kc, c0) loop (160 steps).
// grid (40 q-tiles, 5 ks, 5 w), block 256 (4 waves, tile 128q x 128k).
// ---------------------------------------------------------------------------
__global__ __launch_bounds__(256) void attn_mfma(
    const __bf16* __restrict__ qH, const __bf16* __restrict__ qL,
    const __bf16* __restrict__ kH, const __bf16* __restrict__ kL,
    float* __restrict__ gpart) {
    __shared__ __bf16 sQ[2][128 * 64];
    __shared__ __bf16 sK[2][128 * 64];
    __shared__ float sRed[2][128];
    const int qt = blockIdx.x;  // 0..39
    const int ks = blockIdx.y, wy = blockIdx.z;
    const int sq = qt >> 3, q0 = (qt & 7) * 128;
    const int tid = threadIdx.x;
    const int wv = tid >> 6, l = tid & 63;
    const int wq = (wv >> 1) * 64;
    const int kh = wv & 1;
    const int wk = kh * 64;
    const __bf16* qSrcH = qH + (size_t)(wy * NS + sq) * CHW + (size_t)q0 * CDIM;
    const __bf16* qSrcL = qL + (size_t)(wy * NS + sq) * CHW + (size_t)q0 * CDIM;
    const __bf16* kBaseH = kH + (size_t)(wy * NS + ks) * CHW;
    const __bf16* kBaseL = kL + (size_t)(wy * NS + ks) * CHW;

    float qmax[4][4];
    #pragma unroll
    for (int i = 0; i < 4; ++i)
        #pragma unroll
        for (int q = 0; q < 4; ++q) qmax[i][q] = -INFINITY;

    const int fr = l & 15, cf = l >> 4;
    const int ehi = (cf ^ (fr & 7)) * 8;

    constexpr int NC = CDIM / 32;  // 20 c-steps per kc

    // prologue: stage (kc=0, c0=0) into buf 0
    stage_tile(qSrcH, qSrcL, sQ[0], wv, l, 0);
    stage_tile(kBaseH, kBaseL, sK[0], wv, l, 0);
    __syncthreads();

    for (int kci = 0; kci < 8; ++kci) {
        f32x4 acc[4][4];
        #pragma unroll
        for (int i = 0; i < 4; ++i)
            #pragma unroll
            for (int j = 0; j < 4; ++j) acc[i][j] = (f32x4){0.f, 0.f, 0.f, 0.f};

        for (int ci = 0; ci < NC; ++ci) {
            const int step = kci * NC + ci;
            const int cur = step & 1;
            // issue next step's stage (possibly next kc chunk)
            int nc = ci + 1, nkc = kci;
            if (nc == NC) { nc = 0; ++nkc; }
            if (nkc < 8) {
                stage_tile(qSrcH, qSrcL, sQ[cur ^ 1], wv, l, nc * 32);
                stage_tile(kBaseH + (size_t)(nkc * 128) * CDIM,
                           kBaseL + (size_t)(nkc * 128) * CDIM,
                           sK[cur ^ 1], wv, l, nc * 32);
            }
            bf16x8 aH[4], aL[4], bH[4], bL[4];
            #pragma unroll
            for (int i = 0; i < 4; ++i) {
                const int ra = (wq + i * 16 + fr) * 64;
                const int rb = (wk + i * 16 + fr) * 64;
                aH[i] = *reinterpret_cast<const bf16x8*>(&sQ[cur][ra + ehi]);
                aL[i] = *reinterpret_cast<const bf16x8*>(&sQ[cur][ra + (ehi ^ 32)]);
                bH[i] = *reinterpret_cast<const bf16x8*>(&sK[cur][rb + ehi]);
                bL[i] = *reinterpret_cast<const bf16x8*>(&sK[cur][rb + (ehi ^ 32)]);
            }
            __builtin_amdgcn_s_setprio(1);
            #pragma unroll
            for (int i = 0; i < 4; ++i)
                #pragma unroll
                for (int j = 0; j < 4; ++j) {
                    acc[i][j] = __builtin_amdgcn_mfma_f32_16x16x32_bf16(
                        aH[i], bH[j], acc[i][j], 0, 0, 0);
                    acc[i][j] = __builtin_amdgcn_mfma_f32_16x16x32_bf16(
                        aH[i], bL[j], acc[i][j], 0, 0, 0);
                    acc[i][j] = __builtin_amdgcn_mfma_f32_16x16x32_bf16(
                        aL[i], bH[j], acc[i][j], 0, 0, 0);
                }
            __builtin_amdgcn_s_setprio(0);
            __syncthreads();  // single barrier per step (drain + flip)
        }
        #pragma unroll
        for (int i = 0; i < 4; ++i)
            #pragma unroll
            for (int q = 0; q < 4; ++q) {
                float m = fmaxf(fmaxf(acc[i][0][q], acc[i][1][q]),
                                fmaxf(acc[i][2][q], acc[i][3][q]));
                qmax[i][q] = fmaxf(qmax[i][q], m);
            }
    }
    // reduce max over k (lane groups of 16 share q rows)
    #pragma unroll
    for (int i = 0; i < 4; ++i)
        #pragma unroll
        for (int q = 0; q < 4; ++q) {
            float v = qmax[i][q];
            v = fmaxf(v, __shfl_xor(v, 1));
            v = fmaxf(v, __shfl_xor(v, 2));
            v = fmaxf(v, __shfl_xor(v, 4));
            v = fmaxf(v, __shfl_xor(v, 8));
            qmax[i][q] = v;
        }
    if ((l & 15) == 0) {
        const int g = l >> 4;
        #pragma unroll
        for (int i = 0; i < 4; ++i)
            #pragma unroll
            for (int q = 0; q < 4; ++q)
                sRed[kh][wq + i * 16 + g * 4 + q] = qmax[i][q];
    }
    __syncthreads();
    if (tid < 128) {
        float m = fmaxf(sRed[0][tid], sRed[1][tid]);
        gpart[(size_t)(wy * NS + ks) * (NS * HWDIM) + sq * HWDIM + q0 + tid] =
            m * QK_SCALE;
    }
}

// ---------------------------------------------------------------------------
// mean over key shots -> softmax over hw per (way, sq) -> argmax mask indices
// grid 25 = (w, sq), block 256 (4 hw each).
// ---------------------------------------------------------------------------
__global__ __launch_bounds__(256) void softmax_mask(const float* __restrict__ gpart,
                                                    int* __restrict__ gIdx,
                                                    int* __restrict__ gCnt) {
    const int bb = blockIdx.x;
    const int w = bb / NS, sq = bb % NS;
    const int tid = threadIdx.x;
    __shared__ float sred[256];
    __shared__ int sCnt;

    float v[4];
    #pragma unroll
    for (int i = 0; i < 4; ++i) {
        int hw = tid + 256 * i;
        float s = 0.f;
        #pragma unroll
        for (int ks = 0; ks < NS; ++ks)
            s += gpart[(size_t)(w * NS + ks) * (NS * HWDIM) + sq * HWDIM + hw];
        v[i] = s * 0.2f;
    }
    float m = fmaxf(fmaxf(v[0], v[1]), fmaxf(v[2], v[3]));
    sred[tid] = m;
    __syncthreads();
    for (int s = 128; s > 0; s >>= 1) {
        if (tid < s) sred[tid] = fmaxf(sred[tid], sred[tid + s]);
        __syncthreads();
    }
    float rowmax = sred[0];
    __syncthreads();
    float e[4], ls = 0.f;
    #pragma unroll
    for (int i = 0; i < 4; ++i) { e[i] = expf(v[i] - rowmax); ls += e[i]; }
    sred[tid] = ls;
    __syncthreads();
    for (int s = 128; s > 0; s >>= 1) {
        if (tid < s) sred[tid] += sred[tid + s];
        __syncthreads();
    }
    float ssum = sred[0];
    __syncthreads();
    float p[4], pm = 0.f;
    #pragma unroll
    for (int i = 0; i < 4; ++i) { p[i] = e[i] / ssum; pm = fmaxf(pm, p[i]); }
    sred[tid] = pm;
    __syncthreads();
    for (int s = 128; s > 0; s >>= 1) {
        if (tid < s) sred[tid] = fmaxf(sred[tid], sred[tid + s]);
        __syncthreads();
    }
    float pmax = sred[0];
    if (tid == 0) sCnt = 0;
    __syncthreads();
    #pragma unroll
    for (int i = 0; i < 4; ++i) {
        if (p[i] == pmax) {
            int slot = atomicAdd(&sCnt, 1);
            gIdx[bb * HWDIM + slot] = tid + 256 * i;
        }
    }
    __syncthreads();
    if (tid == 0) gCnt[bb] = sCnt;
}

// ---------------------------------------------------------------------------
// inv_nrm per (bb,hw) row: 1/max(sqrt(sum_c y^2), eps). y = hi+lo, [bb][hw][c].
// grid 1600 (16 rows/block), block 256 (16 lanes per row).
// ---------------------------------------------------------------------------
__global__ __launch_bounds__(256) void nrm_k(const __bf16* __restrict__ yH,
                                             const __bf16* __restrict__ yL,
                                             float* __restrict__ inv) {
    const int row = blockIdx.x * 16 + (threadIdx.x >> 4);
    const int cq = threadIdx.x & 15;
    const size_t base = (size_t)row * CDIM;
    float s = 0.f;
    #pragma unroll
    for (int i = 0; i < 10; ++i) {
        int c = i * 64 + cq * 4;
        bf16x4 h = *reinterpret_cast<const bf16x4*>(&yH[base + c]);
        bf16x4 lo = *reinterpret_cast<const bf16x4*>(&yL[base + c]);
        #pragma unroll
        for (int q = 0; q < 4; ++q) {
            float x = (float)h[q] + (float)lo[q];
            s = fmaf(x, x, s);
        }
    }
    s += __shfl_xor(s, 1);
    s += __shfl_xor(s, 2);
    s += __shfl_xor(s, 4);
    s += __shfl_xor(s, 8);
    if (cq == 0) inv[row] = 1.0f / fmaxf(sqrtf(s), 1e-12f);
}

// ---------------------------------------------------------------------------
// seeds[bb,c] = sum over masked hw of y[bb,hw,c]*inv[bb,hw]
// grid 25, block 640.
// ---------------------------------------------------------------------------
__global__ __launch_bounds__(640) void seeds_k(const __bf16* __restrict__ yH,
                                               const __bf16* __restrict__ yL,
                                               const float* __restrict__ inv,
                                               const int* __restrict__ gIdx,
                                               const int* __restrict__ gCnt,
                                               float* __restrict__ seeds) {
    const int bb = blockIdx.x, c = threadIdx.x;
    const int cnt = gCnt[bb];
    float s = 0.f;
    for (int e = 0; e < cnt; ++e) {
        int hw = gIdx[bb * HWDIM + e];
        size_t off = (size_t)bb * CHW + (size_t)hw * CDIM + c;
        s += ((float)yH[off] + (float)yL[off]) * inv[bb * HWDIM + hw];
    }
    seeds[bb * CDIM + c] = s;
}

// ---------------------------------------------------------------------------
// cm[way,o,hw] = sum_k inv[(way,k),hw] * sum_c y[(way,k),hw,c]*seeds[o*5+k,c]
// grid (256, 5), block 256 (wave per hw row).
// ---------------------------------------------------------------------------
__global__ __launch_bounds__(256) void cm_k(const __bf16* __restrict__ yH,
                                            const __bf16* __restrict__ yL,
                                            const float* __restrict__ inv,
                                            const float* __restrict__ seeds,
                                            float* __restrict__ cm) {
    __shared__ float sS[BDIM * CDIM];  // 64000 B
    const int way = blockIdx.y;
    const int tid = threadIdx.x, wv = tid >> 6, l = tid & 63;
    const int hw = blockIdx.x * 4 + wv;
    for (int e = tid; e < BDIM * CDIM; e += 256) sS[e] = seeds[e];
    __syncthreads();
    float acc[NW] = {0.f, 0.f, 0.f, 0.f, 0.f};
    for (int k = 0; k < NS; ++k) {
        const size_t base = (size_t)(way * NS + k) * CHW + (size_t)hw * CDIM;
        float t[NW] = {0.f, 0.f, 0.f, 0.f, 0.f};
        #pragma unroll
        for (int i = 0; i < 5; ++i) {
            int c = (i * 64 + l) * 2;
            bf16x2 h = *reinterpret_cast<const bf16x2*>(&yH[base + c]);
            bf16x2 lo = *reinterpret_cast<const bf16x2*>(&yL[base + c]);
            float x0 = (float)h[0] + (float)lo[0];
            float x1 = (float)h[1] + (float)lo[1];
            #pragma unroll
            for (int o = 0; o < NW; ++o) {
                t[o] = fmaf(x0, sS[(o * NS + k) * CDIM + c], t[o]);
                t[o] = fmaf(x1, sS[(o * NS + k) * CDIM + c + 1], t[o]);
            }
        }
        float iv = inv[(way * NS + k) * HWDIM + hw];
        #pragma unroll
        for (int o = 0; o < NW; ++o) acc[o] = fmaf(t[o], iv, acc[o]);
    }
    #pragma unroll
    for (int o = 0; o < NW; ++o) {
        float v = acc[o];
        v += __shfl_xor(v, 1);
        v += __shfl_xor(v, 2);
        v += __shfl_xor(v, 4);
        v += __shfl_xor(v, 8);
        v += __shfl_xor(v, 16);
        v += __shfl_xor(v, 32);
        if (l == 0) cm[(size_t)(way * NW + o) * HWDIM + hw] = v;
    }
}

// ---------------------------------------------------------------------------
// in-place min-max normalize each row of 1024. grid 25, block 256.
// ---------------------------------------------------------------------------
__global__ __launch_bounds__(256) void minmax_kernel(float* __restrict__ cm) {
    const int row = blockIdx.x;
    const int tid = threadIdx.x;
    __shared__ float smn[256], smx[256];
    float v[4];
    #pragma unroll
    for (int i = 0; i < 4; ++i) v[i] = cm[(size_t)row * HWDIM + tid + 256 * i];
    float mn = fminf(fminf(v[0], v[1]), fminf(v[2], v[3]));
    float mx = fmaxf(fmaxf(v[0], v[1]), fmaxf(v[2], v[3]));
    smn[tid] = mn;
    smx[tid] = mx;
    __syncthreads();
    for (int s = 128; s > 0; s >>= 1) {
        if (tid < s) {
            smn[tid] = fminf(smn[tid], smn[tid + s]);
            smx[tid] = fmaxf(smx[tid], smx[tid + s]);
        }
        __syncthreads();
    }
    float cmin = smn[0], cmax = smx[0];
    float den = cmax - cmin + 1e-12f;
    #pragma unroll
    for (int i = 0; i < 4; ++i)
        cm[(size_t)row * HWDIM + tid + 256 * i] = (v[i] - cmin) / den;
}

// ---------------------------------------------------------------------------
// proto partials + reduce.
// ---------------------------------------------------------------------------
__global__ __launch_bounds__(128) void proto_part_k(const __bf16* __restrict__ yH,
                                                    const __bf16* __restrict__ yL,
                                                    const float* __restrict__ cmn,
                                                    float* __restrict__ part) {
    const int w = blockIdx.x, cc = blockIdx.y, hs = blockIdx.z;
    const int c = cc * 128 + threadIdx.x;
    float s = 0.f;
    for (int i = 0; i < 640; ++i) {
        int g = hs * 640 + i, sh = g >> 10, hw = g & 1023;
        size_t off = (size_t)(w * NS + sh) * CHW + (size_t)hw * CDIM + c;
        s = fmaf((float)yH[off] + (float)yL[off],
                 cmn[(w * NS + sh) * HWDIM + hw], s);
    }
    part[((w * 5 + cc) * 8 + hs) * 128 + threadIdx.x] = s;
}

__global__ __launch_bounds__(128) void proto_red_k(const float* __restrict__ part,
                                                   float* __restrict__ out) {
    const int bid = blockIdx.x;  // w*5+cc
    float s = 0.f;
    #pragma unroll
    for (int hs = 0; hs < 8; ++hs) s += part[(bid * 8 + hs) * 128 + threadIdx.x];
    const int w = bid / 5, cc = bid % 5;
    out[w * CDIM + cc * 128 + threadIdx.x] = s * (1.0f / 5120.0f);
}

// ---------------------------------------------------------------------------
extern "C" void kernel_launch(void* const* d_in, const int* in_sizes, int n_in,
                              void* d_out, int out_size, void* d_ws, size_t ws_size,
                              hipStream_t stream) {
    const float* x5 = (const float*)d_in[0];
    const float* Wc = (const float*)d_in[1];
    const float* bc = (const float*)d_in[2];
    const float* Wq = (const float*)d_in[3];
    const float* bq = (const float*)d_in[4];
    const float* Wk = (const float*)d_in[5];
    const float* bk = (const float*)d_in[6];
    float* out = (float*)d_out;

    __bf16* big = (__bf16*)d_ws;
    __bf16* A_hi = big;
    __bf16* A_lo = big + (size_t)NBIG;
    __bf16* B_hi = big + (size_t)2 * NBIG;
    __bf16* B_lo = big + (size_t)3 * NBIG;
    __bf16* C_hi = big + (size_t)4 * NBIG;
    __bf16* C_lo = big + (size_t)5 * NBIG;
    __bf16* wp = big + (size_t)6 * NBIG;
    __bf16* WcH = wp;
    __bf16* WcL = wp + WSZ;
    __bf16* WqH = wp + 2 * WSZ;
    __bf16* WqL = wp + 3 * WSZ;
    __bf16* WkH = wp + 4 * WSZ;
    __bf16* WkL = wp + 5 * WSZ;
    float* fp = (float*)(wp + 6 * WSZ);
    float* gpart = fp;                    // 128000
    float* invb = fp + 128000;            // 25600
    float* seedsb = fp + 153600;          // 16000
    float* cmb = fp + 169600;             // 25600
    float* partb = fp + 195200;           // 25600
    int* gIdx = (int*)(fp + 220800);      // 25600
    int* gCnt = gIdx + BDIM * HWDIM;      // 25

    const int W4 = WSZ / 4;
    split_f32<<<dim3((W4 + 255) / 256), 256, 0, stream>>>(Wc, WcH, WcL, W4);
    split_f32<<<dim3((W4 + 255) / 256), 256, 0, stream>>>(Wq, WqH, WqL, W4);
    split_f32<<<dim3((W4 + 255) / 256), 256, 0, stream>>>(Wk, WkH, WkL, W4);
    tsplit<<<dim3(32, 20, 25), 256, 0, stream>>>(x5, A_hi, A_lo);

    dim3 gG(8, 5, 25);
    // y1 = conv(x,Wc)+x
    conv_mfma<1><<<gG, 256, 0, stream>>>(A_hi, A_lo, WcH, WcL, bc, B_hi, B_lo);
    // y2 = conv(y1,Wq)
    conv_mfma<0><<<gG, 256, 0, stream>>>(B_hi, B_lo, WqH, WqL, bq, C_hi, C_lo);
    // xq = conv(y2,Wq)  (into B, y1 dead)
    conv_mfma<0><<<gG, 256, 0, stream>>>(C_hi, C_lo, WqH, WqL, bq, B_hi, B_lo);
    // xk = conv(y2,Wk)  (into A, x dead)
    conv_mfma<0><<<gG, 256, 0, stream>>>(C_hi, C_lo, WkH, WkL, bk, A_hi, A_lo);

    attn_mfma<<<dim3(40, 5, 5), 256, 0, stream>>>(B_hi, B_lo, A_hi, A_lo, gpart);
    softmax_mask<<<25, 256, 0, stream>>>(gpart, gIdx, gCnt);
    nrm_k<<<1600, 256, 0, stream>>>(C_hi, C_lo, invb);
    seeds_k<<<25, 640, 0, stream>>>(C_hi, C_lo, invb, gIdx, gCnt, seedsb);
    cm_k<<<dim3(256, 5), 256, 0, stream>>>(C_hi, C_lo, invb, seedsb, cmb);
    minmax_kernel<<<25, 256, 0, stream>>>(cmb);
    proto_part_k<<<dim3(5, 5, 8), 128, 0, stream>>>(C_hi, C_lo, cmb, partb);
    proto_red_k<<<25, 128, 0, stream>>>(partb, out);
}

// Round 5
// 1007.019 us; speedup vs baseline: 1.0763x; 1.0746x over previous
//
#include <hip/hip_runtime.h>
#include <math.h>

#define NW 5
#define NS 5
#define CDIM 640
#define HWDIM 1024
#define BDIM 25
constexpr int CHW = CDIM * HWDIM;                 // 655360
constexpr int NBIG = BDIM * CHW;                  // 16,384,000 elems
constexpr int WSZ = CDIM * CDIM;                  // 409,600
constexpr float QK_SCALE = 0.03952847075210474f;  // 1/sqrt(640)

typedef __attribute__((ext_vector_type(4))) float f32x4;
typedef __attribute__((ext_vector_type(8))) __bf16 bf16x8;
typedef __attribute__((ext_vector_type(4))) __bf16 bf16x4;
typedef __attribute__((ext_vector_type(2))) __bf16 bf16x2;

__device__ __forceinline__ void load_lds16(const __bf16* g, __bf16* l) {
    __builtin_amdgcn_global_load_lds(
        (const __attribute__((address_space(1))) void*)g,
        (__attribute__((address_space(3))) void*)l, 16, 0, 0);
}

// ---------------------------------------------------------------------------
// split fp32 -> (hi, lo) bf16, same layout. n4 = n/4.
// ---------------------------------------------------------------------------
__global__ __launch_bounds__(256) void split_f32(const float* __restrict__ s,
                                                 __bf16* __restrict__ dH,
                                                 __bf16* __restrict__ dL, int n4) {
    int i = blockIdx.x * 256 + threadIdx.x;
    if (i >= n4) return;
    f32x4 v = reinterpret_cast<const f32x4*>(s)[i];
    bf16x4 h, lo;
    #pragma unroll
    for (int q = 0; q < 4; ++q) {
        __bf16 hh = (__bf16)v[q];
        h[q] = hh;
        lo[q] = (__bf16)(v[q] - (float)hh);
    }
    reinterpret_cast<bf16x4*>(dH)[i] = h;
    reinterpret_cast<bf16x4*>(dL)[i] = lo;
}

// ---------------------------------------------------------------------------
// transpose [b][c][hw] fp32 -> [b][hw][c] (hi,lo) bf16. 32x32 tiles.
// ---------------------------------------------------------------------------
__global__ __launch_bounds__(256) void tsplit(const float* __restrict__ x,
                                              __bf16* __restrict__ dH,
                                              __bf16* __restrict__ dL) {
    __shared__ float sT[32][33];
    const int hw0 = blockIdx.x * 32, c0 = blockIdx.y * 32, b = blockIdx.z;
    const int t = threadIdx.x;
    const int r = t >> 3, q4 = (t & 7) * 4;
    f32x4 v = *reinterpret_cast<const f32x4*>(
        &x[(size_t)b * CHW + (size_t)(c0 + r) * HWDIM + hw0 + q4]);
    #pragma unroll
    for (int i = 0; i < 4; ++i) sT[r][q4 + i] = v[i];
    __syncthreads();
    bf16x4 h, lo;
    #pragma unroll
    for (int i = 0; i < 4; ++i) {
        float xv = sT[q4 + i][r];
        __bf16 hh = (__bf16)xv;
        h[i] = hh;
        lo[i] = (__bf16)(xv - (float)hh);
    }
    size_t off = (size_t)b * CHW + (size_t)(hw0 + r) * CDIM + c0 + q4;
    *reinterpret_cast<bf16x4*>(&dH[off]) = h;
    *reinterpret_cast<bf16x4*>(&dL[off]) = lo;
}

// ---------------------------------------------------------------------------
// transposed split of (Wc + I): out[ci][t] = Wc[t][ci] + (t==ci), hi/lo bf16.
// grid (20, 20), block 256.
// ---------------------------------------------------------------------------
__global__ __launch_bounds__(256) void wtsplit(const float* __restrict__ W,
                                               __bf16* __restrict__ dH,
                                               __bf16* __restrict__ dL) {
    __shared__ float sT[32][33];
    const int ci0 = blockIdx.x * 32, t0 = blockIdx.y * 32;
    const int t = threadIdx.x;
    const int r = t >> 3, q4 = (t & 7) * 4;
    f32x4 v = *reinterpret_cast<const f32x4*>(&W[(size_t)(t0 + r) * CDIM + ci0 + q4]);
    #pragma unroll
    for (int i = 0; i < 4; ++i) sT[r][q4 + i] = v[i];
    __syncthreads();
    bf16x4 h, lo;
    #pragma unroll
    for (int i = 0; i < 4; ++i) {
        float xv = sT[q4 + i][r];  // = W[t0+q4+i][ci0+r]
        if (t0 + q4 + i == ci0 + r) xv += 1.0f;
        __bf16 hh = (__bf16)xv;
        h[i] = hh;
        lo[i] = (__bf16)(xv - (float)hh);
    }
    size_t off = (size_t)(ci0 + r) * CDIM + t0 + q4;
    *reinterpret_cast<bf16x4*>(&dH[off]) = h;
    *reinterpret_cast<bf16x4*>(&dL[off]) = lo;
}

__global__ void zero_k(float* __restrict__ p) { p[threadIdx.x] = 0.0f; }

// B2[o] = sum_t Wq[o,t]*bc[t] + bq[o]   (fp32, one block of 640)
__global__ void bias1_k(const float* __restrict__ Wq, const float* __restrict__ bc,
                        const float* __restrict__ bq, float* __restrict__ B2) {
    const int o = threadIdx.x;
    float s = bq[o];
    for (int t = 0; t < CDIM; ++t) s = fmaf(Wq[(size_t)o * CDIM + t], bc[t], s);
    B2[o] = s;
}

// ===========================================================================
// Swizzled LDS staging (both-sides XOR): tile rows of 64 bf16 (cols 0-31 hi,
// 32-63 lo). Physical 16B chunk = logical ^ (row&7), applied via per-lane
// global source address; reads use ehi = (cf ^ (fr&7))*8.
// ===========================================================================
template <int NL>
__device__ __forceinline__ void stage_rows(const __bf16* __restrict__ srcH,
                                           const __bf16* __restrict__ srcL,
                                           __bf16* lds, int wv, int l, int c0) {
    const int lch = (l & 7) ^ (l >> 3);
    const int scol = (lch & 3) * 8;
    const int srw = l >> 3;
    const __bf16* src = (lch & 4) ? srcL : srcH;
    #pragma unroll
    for (int i = 0; i < NL; ++i) {
        const int r0 = wv * (8 * NL) + i * 8;
        load_lds16(&src[(size_t)(r0 + srw) * CDIM + c0 + scol], &lds[r0 * 64]);
    }
}

// ---------------------------------------------------------------------------
// small split-GEMM (product W2 = Wq * (Wc+I)): old 128x128/4-wave structure.
// out[hw][o] = sum_c in[hw,c]*W[o,c] + bias[o]; used with zero bias.
// ---------------------------------------------------------------------------
__global__ __launch_bounds__(256) void gemm_sm(
    const __bf16* __restrict__ inH, const __bf16* __restrict__ inL,
    const __bf16* __restrict__ wH, const __bf16* __restrict__ wL,
    const float* __restrict__ bias,
    __bf16* __restrict__ outH, __bf16* __restrict__ outL) {
    __shared__ __bf16 sA[128 * 64];
    __shared__ __bf16 sB[128 * 64];
    const int hw0 = blockIdx.x * 128;
    const int o0 = blockIdx.y * 128;
    const int tid = threadIdx.x;
    const int wv = tid >> 6, l = tid & 63;
    const int wo = (wv >> 1) * 64, wh = (wv & 1) * 64;

    const __bf16* wSrcH = wH + (size_t)o0 * CDIM;
    const __bf16* wSrcL = wL + (size_t)o0 * CDIM;
    const __bf16* iSrcH = inH + (size_t)hw0 * CDIM;
    const __bf16* iSrcL = inL + (size_t)hw0 * CDIM;

    f32x4 acc[4][4];
    #pragma unroll
    for (int i = 0; i < 4; ++i)
        #pragma unroll
        for (int j = 0; j < 4; ++j) acc[i][j] = (f32x4){0.f, 0.f, 0.f, 0.f};

    const int fr = l & 15, cf = l >> 4;
    const int ehi = (cf ^ (fr & 7)) * 8;

    for (int c0 = 0; c0 < CDIM; c0 += 32) {
        stage_rows<4>(wSrcH, wSrcL, sA, wv, l, c0);
        stage_rows<4>(iSrcH, iSrcL, sB, wv, l, c0);
        __syncthreads();
        bf16x8 aH[4], aL[4], bH[4], bL[4];
        #pragma unroll
        for (int i = 0; i < 4; ++i) {
            const int ra = (wo + i * 16 + fr) * 64;
            const int rb = (wh + i * 16 + fr) * 64;
            aH[i] = *reinterpret_cast<const bf16x8*>(&sA[ra + ehi]);
            aL[i] = *reinterpret_cast<const bf16x8*>(&sA[ra + (ehi ^ 32)]);
            bH[i] = *reinterpret_cast<const bf16x8*>(&sB[rb + ehi]);
            bL[i] = *reinterpret_cast<const bf16x8*>(&sB[rb + (ehi ^ 32)]);
        }
        #pragma unroll
        for (int i = 0; i < 4; ++i)
            #pragma unroll
            for (int j = 0; j < 4; ++j) {
                acc[i][j] = __builtin_amdgcn_mfma_f32_16x16x32_bf16(
                    aH[i], bH[j], acc[i][j], 0, 0, 0);
                acc[i][j] = __builtin_amdgcn_mfma_f32_16x16x32_bf16(
                    aH[i], bL[j], acc[i][j], 0, 0, 0);
                acc[i][j] = __builtin_amdgcn_mfma_f32_16x16x32_bf16(
                    aL[i], bH[j], acc[i][j], 0, 0, 0);
            }
        __syncthreads();
    }

    const int og = (l >> 4) * 4;
    const int cl = l & 15;
    #pragma unroll
    for (int i = 0; i < 4; ++i) {
        const int o = o0 + wo + i * 16 + og;
        const f32x4 bs = *reinterpret_cast<const f32x4*>(&bias[o]);
        #pragma unroll
        for (int j = 0; j < 4; ++j) {
            const int hw = hw0 + wh + j * 16 + cl;
            const size_t off = (size_t)hw * CDIM + o;
            bf16x4 oh, ol;
            #pragma unroll
            for (int q = 0; q < 4; ++q) {
                float r = acc[i][j][q] + bs[q];
                __bf16 hh = (__bf16)r;
                oh[q] = hh;
                ol[q] = (__bf16)(r - (float)hh);
            }
            *reinterpret_cast<bf16x4*>(&outH[off]) = oh;
            *reinterpret_cast<bf16x4*>(&outL[off]) = ol;
        }
    }
}

// ---------------------------------------------------------------------------
// big conv: block tile 128o x 256hw, 4 waves of 64o x 128hw, single-buffer.
// out[b,hw,o] = sum_c in[b,hw,c]*A[o,c] + bias[o']; A/out routed by o-segment
// (segDiv o-tiles per segment of 640 channels). grid (hw/256, nOtiles, 25).
// ---------------------------------------------------------------------------
__global__ __launch_bounds__(256, 2) void conv_big(
    const __bf16* __restrict__ inH, const __bf16* __restrict__ inL,
    const __bf16* __restrict__ A0h, const __bf16* __restrict__ A0l,
    const __bf16* __restrict__ A1h, const __bf16* __restrict__ A1l,
    const float* __restrict__ bias,
    __bf16* __restrict__ O0h, __bf16* __restrict__ O0l,
    __bf16* __restrict__ O1h, __bf16* __restrict__ O1l) {
    __shared__ __bf16 sA[128 * 64];  // weights [o][hi|lo]
    __shared__ __bf16 sB[256 * 64];  // input   [hw][hi|lo]
    const int hw0 = blockIdx.x * 256;
    const int oy = blockIdx.y;
    const int seg = oy / 5;
    const int o0 = (oy % 5) * 128;
    const int b = blockIdx.z;
    const int tid = threadIdx.x;
    const int wv = tid >> 6, l = tid & 63;
    const int wo = (wv >> 1) * 64;   // o sub-tile (2 groups of 64)
    const int wh = (wv & 1) * 128;   // hw sub-tile (2 groups of 128)
    const size_t inBase = (size_t)b * CHW;

    const __bf16* Ah = seg ? A1h : A0h;
    const __bf16* Al = seg ? A1l : A0l;
    __bf16* OhP = seg ? O1h : O0h;
    __bf16* OlP = seg ? O1l : O0l;
    const __bf16* aSrcH = Ah + (size_t)o0 * CDIM;
    const __bf16* aSrcL = Al + (size_t)o0 * CDIM;
    const __bf16* bSrcH = inH + inBase + (size_t)hw0 * CDIM;
    const __bf16* bSrcL = inL + inBase + (size_t)hw0 * CDIM;

    f32x4 acc[4][8];
    #pragma unroll
    for (int i = 0; i < 4; ++i)
        #pragma unroll
        for (int j = 0; j < 8; ++j) acc[i][j] = (f32x4){0.f, 0.f, 0.f, 0.f};

    const int fr = l & 15, cf = l >> 4;
    const int ehi = (cf ^ (fr & 7)) * 8;

    for (int c0 = 0; c0 < CDIM; c0 += 32) {
        stage_rows<4>(aSrcH, aSrcL, sA, wv, l, c0);
        stage_rows<8>(bSrcH, bSrcL, sB, wv, l, c0);
        __syncthreads();
        bf16x8 aH[4], aL[4];
        #pragma unroll
        for (int i = 0; i < 4; ++i) {
            const int ra = (wo + i * 16 + fr) * 64;
            aH[i] = *reinterpret_cast<const bf16x8*>(&sA[ra + ehi]);
            aL[i] = *reinterpret_cast<const bf16x8*>(&sA[ra + (ehi ^ 32)]);
        }
        #pragma unroll
        for (int jh = 0; jh < 2; ++jh) {
            bf16x8 bH[4], bL[4];
            #pragma unroll
            for (int jj = 0; jj < 4; ++jj) {
                const int rb = (wh + (jh * 4 + jj) * 16 + fr) * 64;
                bH[jj] = *reinterpret_cast<const bf16x8*>(&sB[rb + ehi]);
                bL[jj] = *reinterpret_cast<const bf16x8*>(&sB[rb + (ehi ^ 32)]);
            }
            #pragma unroll
            for (int i = 0; i < 4; ++i)
                #pragma unroll
                for (int jj = 0; jj < 4; ++jj) {
                    const int j = jh * 4 + jj;
                    acc[i][j] = __builtin_amdgcn_mfma_f32_16x16x32_bf16(
                        aH[i], bH[jj], acc[i][j], 0, 0, 0);
                    acc[i][j] = __builtin_amdgcn_mfma_f32_16x16x32_bf16(
                        aH[i], bL[jj], acc[i][j], 0, 0, 0);
                    acc[i][j] = __builtin_amdgcn_mfma_f32_16x16x32_bf16(
                        aL[i], bH[jj], acc[i][j], 0, 0, 0);
                }
        }
        __syncthreads();
    }

    const int og = (l >> 4) * 4;
    const int cl = l & 15;
    #pragma unroll
    for (int i = 0; i < 4; ++i) {
        const int oLoc = o0 + wo + i * 16 + og;              // within segment
        const f32x4 bs = *reinterpret_cast<const f32x4*>(&bias[oy * 128 + wo + i * 16 + og]);
        #pragma unroll
        for (int j = 0; j < 8; ++j) {
            const int hw = hw0 + wh + j * 16 + cl;
            const size_t off = inBase + (size_t)hw * CDIM + oLoc;
            bf16x4 oh, ol;
            #pragma unroll
            for (int q = 0; q < 4; ++q) {
                float r = acc[i][j][q] + bs[q];
                __bf16 hh = (__bf16)r;
                oh[q] = hh;
                ol[q] = (__bf16)(r - (float)hh);
            }
            *reinterpret_cast<bf16x4*>(&OhP[off]) = oh;
            *reinterpret_cast<bf16x4*>(&OlP[off]) = ol;
        }
    }
}

// ---------------------------------------------------------------------------
// attention scores + per-key spatial max. Block tile 128q x 256k, 4 waves of
// 64q x 128k, single-buffer LDS, 4 kc chunks of 256 keys.
// grid (40 q-tiles, 5 ks, 5 w), block 256.
// ---------------------------------------------------------------------------
__global__ __launch_bounds__(256, 2) void attn_mfma2(
    const __bf16* __restrict__ qH, const __bf16* __restrict__ qL,
    const __bf16* __restrict__ kH, const __bf16* __restrict__ kL,
    float* __restrict__ gpart) {
    __shared__ __bf16 sQ[128 * 64];
    __shared__ __bf16 sK[256 * 64];
    __shared__ float sRed[2][128];
    const int qt = blockIdx.x;  // 0..39
    const int ks = blockIdx.y, wy = blockIdx.z;
    const int sq = qt >> 3, q0 = (qt & 7) * 128;
    const int tid = threadIdx.x;
    const int wv = tid >> 6, l = tid & 63;
    const int wq = (wv >> 1) * 64;   // q sub-tile
    const int kh = wv & 1;
    const int wk = kh * 128;         // k sub-tile
    const __bf16* qSrcH = qH + (size_t)(wy * NS + sq) * CHW + (size_t)q0 * CDIM;
    const __bf16* qSrcL = qL + (size_t)(wy * NS + sq) * CHW + (size_t)q0 * CDIM;
    const __bf16* kBaseH = kH + (size_t)(wy * NS + ks) * CHW;
    const __bf16* kBaseL = kL + (size_t)(wy * NS + ks) * CHW;

    float qmax[4][4];
    #pragma unroll
    for (int i = 0; i < 4; ++i)
        #pragma unroll
        for (int q = 0; q < 4; ++q) qmax[i][q] = -INFINITY;

    const int fr = l & 15, cf = l >> 4;
    const int ehi = (cf ^ (fr & 7)) * 8;

    for (int kc = 0; kc < 4; ++kc) {
        const __bf16* kSrcH = kBaseH + (size_t)(kc * 256) * CDIM;
        const __bf16* kSrcL = kBaseL + (size_t)(kc * 256) * CDIM;
        f32x4 acc[4][8];
        #pragma unroll
        for (int i = 0; i < 4; ++i)
            #pragma unroll
            for (int j = 0; j < 8; ++j) acc[i][j] = (f32x4){0.f, 0.f, 0.f, 0.f};

        for (int c0 = 0; c0 < CDIM; c0 += 32) {
            stage_rows<4>(qSrcH, qSrcL, sQ, wv, l, c0);
            stage_rows<8>(kSrcH, kSrcL, sK, wv, l, c0);
            __syncthreads();
            bf16x8 aH[4], aL[4];
            #pragma unroll
            for (int i = 0; i < 4; ++i) {
                const int ra = (wq + i * 16 + fr) * 64;
                aH[i] = *reinterpret_cast<const bf16x8*>(&sQ[ra + ehi]);
                aL[i] = *reinterpret_cast<const bf16x8*>(&sQ[ra + (ehi ^ 32)]);
            }
            __builtin_amdgcn_s_setprio(1);
            #pragma unroll
            for (int jh = 0; jh < 2; ++jh) {
                bf16x8 bH[4], bL[4];
                #pragma unroll
                for (int jj = 0; jj < 4; ++jj) {
                    const int rb = (wk + (jh * 4 + jj) * 16 + fr) * 64;
                    bH[jj] = *reinterpret_cast<const bf16x8*>(&sK[rb + ehi]);
                    bL[jj] = *reinterpret_cast<const bf16x8*>(&sK[rb + (ehi ^ 32)]);
                }
                #pragma unroll
                for (int i = 0; i < 4; ++i)
                    #pragma unroll
                    for (int jj = 0; jj < 4; ++jj) {
                        const int j = jh * 4 + jj;
                        acc[i][j] = __builtin_amdgcn_mfma_f32_16x16x32_bf16(
                            aH[i], bH[jj], acc[i][j], 0, 0, 0);
                        acc[i][j] = __builtin_amdgcn_mfma_f32_16x16x32_bf16(
                            aH[i], bL[jj], acc[i][j], 0, 0, 0);
                        acc[i][j] = __builtin_amdgcn_mfma_f32_16x16x32_bf16(
                            aL[i], bH[jj], acc[i][j], 0, 0, 0);
                    }
            }
            __builtin_amdgcn_s_setprio(0);
            __syncthreads();
        }
        #pragma unroll
        for (int i = 0; i < 4; ++i)
            #pragma unroll
            for (int q = 0; q < 4; ++q) {
                float m = acc[i][0][q];
                #pragma unroll
                for (int j = 1; j < 8; ++j) m = fmaxf(m, acc[i][j][q]);
                qmax[i][q] = fmaxf(qmax[i][q], m);
            }
    }
    // reduce over the 16 k-columns within lane groups
    #pragma unroll
    for (int i = 0; i < 4; ++i)
        #pragma unroll
        for (int q = 0; q < 4; ++q) {
            float v = qmax[i][q];
            v = fmaxf(v, __shfl_xor(v, 1));
            v = fmaxf(v, __shfl_xor(v, 2));
            v = fmaxf(v, __shfl_xor(v, 4));
            v = fmaxf(v, __shfl_xor(v, 8));
            qmax[i][q] = v;
        }
    if ((l & 15) == 0) {
        const int g = l >> 4;
        #pragma unroll
        for (int i = 0; i < 4; ++i)
            #pragma unroll
            for (int q = 0; q < 4; ++q)
                sRed[kh][wq + i * 16 + g * 4 + q] = qmax[i][q];
    }
    __syncthreads();
    if (tid < 128) {
        float m = fmaxf(sRed[0][tid], sRed[1][tid]);
        gpart[(size_t)(wy * NS + ks) * (NS * HWDIM) + sq * HWDIM + q0 + tid] =
            m * QK_SCALE;
    }
}

// ---------------------------------------------------------------------------
// mean over key shots -> softmax over hw per (way, sq) -> argmax mask indices
// ---------------------------------------------------------------------------
__global__ __launch_bounds__(256) void softmax_mask(const float* __restrict__ gpart,
                                                    int* __restrict__ gIdx,
                                                    int* __restrict__ gCnt) {
    const int bb = blockIdx.x;
    const int w = bb / NS, sq = bb % NS;
    const int tid = threadIdx.x;
    __shared__ float sred[256];
    __shared__ int sCnt;

    float v[4];
    #pragma unroll
    for (int i = 0; i < 4; ++i) {
        int hw = tid + 256 * i;
        float s = 0.f;
        #pragma unroll
        for (int ks = 0; ks < NS; ++ks)
            s += gpart[(size_t)(w * NS + ks) * (NS * HWDIM) + sq * HWDIM + hw];
        v[i] = s * 0.2f;
    }
    float m = fmaxf(fmaxf(v[0], v[1]), fmaxf(v[2], v[3]));
    sred[tid] = m;
    __syncthreads();
    for (int s = 128; s > 0; s >>= 1) {
        if (tid < s) sred[tid] = fmaxf(sred[tid], sred[tid + s]);
        __syncthreads();
    }
    float rowmax = sred[0];
    __syncthreads();
    float e[4], ls = 0.f;
    #pragma unroll
    for (int i = 0; i < 4; ++i) { e[i] = expf(v[i] - rowmax); ls += e[i]; }
    sred[tid] = ls;
    __syncthreads();
    for (int s = 128; s > 0; s >>= 1) {
        if (tid < s) sred[tid] += sred[tid + s];
        __syncthreads();
    }
    float ssum = sred[0];
    __syncthreads();
    float p[4], pm = 0.f;
    #pragma unroll
    for (int i = 0; i < 4; ++i) { p[i] = e[i] / ssum; pm = fmaxf(pm, p[i]); }
    sred[tid] = pm;
    __syncthreads();
    for (int s = 128; s > 0; s >>= 1) {
        if (tid < s) sred[tid] = fmaxf(sred[tid], sred[tid + s]);
        __syncthreads();
    }
    float pmax = sred[0];
    if (tid == 0) sCnt = 0;
    __syncthreads();
    #pragma unroll
    for (int i = 0; i < 4; ++i) {
        if (p[i] == pmax) {
            int slot = atomicAdd(&sCnt, 1);
            gIdx[bb * HWDIM + slot] = tid + 256 * i;
        }
    }
    __syncthreads();
    if (tid == 0) gCnt[bb] = sCnt;
}

// ---------------------------------------------------------------------------
// inv_nrm per (bb,hw): 1/max(sqrt(sum_c y^2), eps). grid 1600, block 256.
// ---------------------------------------------------------------------------
__global__ __launch_bounds__(256) void nrm_k(const __bf16* __restrict__ yH,
                                             const __bf16* __restrict__ yL,
                                             float* __restrict__ inv) {
    const int row = blockIdx.x * 16 + (threadIdx.x >> 4);
    const int cq = threadIdx.x & 15;
    const size_t base = (size_t)row * CDIM;
    float s = 0.f;
    #pragma unroll
    for (int i = 0; i < 10; ++i) {
        int c = i * 64 + cq * 4;
        bf16x4 h = *reinterpret_cast<const bf16x4*>(&yH[base + c]);
        bf16x4 lo = *reinterpret_cast<const bf16x4*>(&yL[base + c]);
        #pragma unroll
        for (int q = 0; q < 4; ++q) {
            float x = (float)h[q] + (float)lo[q];
            s = fmaf(x, x, s);
        }
    }
    s += __shfl_xor(s, 1);
    s += __shfl_xor(s, 2);
    s += __shfl_xor(s, 4);
    s += __shfl_xor(s, 8);
    if (cq == 0) inv[row] = 1.0f / fmaxf(sqrtf(s), 1e-12f);
}

// ---------------------------------------------------------------------------
// seeds[bb,c] = sum over masked hw of y[bb,hw,c]*inv[bb,hw]. grid 25, blk 640.
// ---------------------------------------------------------------------------
__global__ __launch_bounds__(640) void seeds_k(const __bf16* __restrict__ yH,
                                               const __bf16* __restrict__ yL,
                                               const float* __restrict__ inv,
                                               const int* __restrict__ gIdx,
                                               const int* __restrict__ gCnt,
                                               float* __restrict__ seeds) {
    const int bb = blockIdx.x, c = threadIdx.x;
    const int cnt = gCnt[bb];
    float s = 0.f;
    for (int e = 0; e < cnt; ++e) {
        int hw = gIdx[bb * HWDIM + e];
        size_t off = (size_t)bb * CHW + (size_t)hw * CDIM + c;
        s += ((float)yH[off] + (float)yL[off]) * inv[bb * HWDIM + hw];
    }
    seeds[bb * CDIM + c] = s;
}

// ---------------------------------------------------------------------------
// cm[way,o,hw] = sum_k inv[(way,k),hw] * sum_c y[(way,k),hw,c]*seeds[o*5+k,c]
// ---------------------------------------------------------------------------
__global__ __launch_bounds__(256) void cm_k(const __bf16* __restrict__ yH,
                                            const __bf16* __restrict__ yL,
                                            const float* __restrict__ inv,
                                            const float* __restrict__ seeds,
                                            float* __restrict__ cm) {
    __shared__ float sS[BDIM * CDIM];  // 64000 B
    const int way = blockIdx.y;
    const int tid = threadIdx.x, wv = tid >> 6, l = tid & 63;
    const int hw = blockIdx.x * 4 + wv;
    for (int e = tid; e < BDIM * CDIM; e += 256) sS[e] = seeds[e];
    __syncthreads();
    float acc[NW] = {0.f, 0.f, 0.f, 0.f, 0.f};
    for (int k = 0; k < NS; ++k) {
        const size_t base = (size_t)(way * NS + k) * CHW + (size_t)hw * CDIM;
        float t[NW] = {0.f, 0.f, 0.f, 0.f, 0.f};
        #pragma unroll
        for (int i = 0; i < 5; ++i) {
            int c = (i * 64 + l) * 2;
            bf16x2 h = *reinterpret_cast<const bf16x2*>(&yH[base + c]);
            bf16x2 lo = *reinterpret_cast<const bf16x2*>(&yL[base + c]);
            float x0 = (float)h[0] + (float)lo[0];
            float x1 = (float)h[1] + (float)lo[1];
            #pragma unroll
            for (int o = 0; o < NW; ++o) {
                t[o] = fmaf(x0, sS[(o * NS + k) * CDIM + c], t[o]);
                t[o] = fmaf(x1, sS[(o * NS + k) * CDIM + c + 1], t[o]);
            }
        }
        float iv = inv[(way * NS + k) * HWDIM + hw];
        #pragma unroll
        for (int o = 0; o < NW; ++o) acc[o] = fmaf(t[o], iv, acc[o]);
    }
    #pragma unroll
    for (int o = 0; o < NW; ++o) {
        float v = acc[o];
        v += __shfl_xor(v, 1);
        v += __shfl_xor(v, 2);
        v += __shfl_xor(v, 4);
        v += __shfl_xor(v, 8);
        v += __shfl_xor(v, 16);
        v += __shfl_xor(v, 32);
        if (l == 0) cm[(size_t)(way * NW + o) * HWDIM + hw] = v;
    }
}

// ---------------------------------------------------------------------------
// in-place min-max normalize each row of 1024. grid 25, block 256.
// ---------------------------------------------------------------------------
__global__ __launch_bounds__(256) void minmax_kernel(float* __restrict__ cm) {
    const int row = blockIdx.x;
    const int tid = threadIdx.x;
    __shared__ float smn[256], smx[256];
    float v[4];
    #pragma unroll
    for (int i = 0; i < 4; ++i) v[i] = cm[(size_t)row * HWDIM + tid + 256 * i];
    float mn = fminf(fminf(v[0], v[1]), fminf(v[2], v[3]));
    float mx = fmaxf(fmaxf(v[0], v[1]), fmaxf(v[2], v[3]));
    smn[tid] = mn;
    smx[tid] = mx;
    __syncthreads();
    for (int s = 128; s > 0; s >>= 1) {
        if (tid < s) {
            smn[tid] = fminf(smn[tid], smn[tid + s]);
            smx[tid] = fmaxf(smx[tid], smx[tid + s]);
        }
        __syncthreads();
    }
    float cmin = smn[0], cmax = smx[0];
    float den = cmax - cmin + 1e-12f;
    #pragma unroll
    for (int i = 0; i < 4; ++i)
        cm[(size_t)row * HWDIM + tid + 256 * i] = (v[i] - cmin) / den;
}

// ---------------------------------------------------------------------------
// proto partials + reduce.
// ---------------------------------------------------------------------------
__global__ __launch_bounds__(128) void proto_part_k(const __bf16* __restrict__ yH,
                                                    const __bf16* __restrict__ yL,
                                                    const float* __restrict__ cmn,
                                                    float* __restrict__ part) {
    const int w = blockIdx.x, cc = blockIdx.y, hs = blockIdx.z;
    const int c = cc * 128 + threadIdx.x;
    float s = 0.f;
    for (int i = 0; i < 640; ++i) {
        int g = hs * 640 + i, sh = g >> 10, hw = g & 1023;
        size_t off = (size_t)(w * NS + sh) * CHW + (size_t)hw * CDIM + c;
        s = fmaf((float)yH[off] + (float)yL[off],
                 cmn[(w * NS + sh) * HWDIM + hw], s);
    }
    part[((w * 5 + cc) * 8 + hs) * 128 + threadIdx.x] = s;
}

__global__ __launch_bounds__(128) void proto_red_k(const float* __restrict__ part,
                                                   float* __restrict__ out) {
    const int bid = blockIdx.x;  // w*5+cc
    float s = 0.f;
    #pragma unroll
    for (int hs = 0; hs < 8; ++hs) s += part[(bid * 8 + hs) * 128 + threadIdx.x];
    const int w = bid / 5, cc = bid % 5;
    out[w * CDIM + cc * 128 + threadIdx.x] = s * (1.0f / 5120.0f);
}

// ---------------------------------------------------------------------------
extern "C" void kernel_launch(void* const* d_in, const int* in_sizes, int n_in,
                              void* d_out, int out_size, void* d_ws, size_t ws_size,
                              hipStream_t stream) {
    const float* x5 = (const float*)d_in[0];
    const float* Wc = (const float*)d_in[1];
    const float* bc = (const float*)d_in[2];
    const float* Wq = (const float*)d_in[3];
    const float* bq = (const float*)d_in[4];
    const float* Wk = (const float*)d_in[5];
    const float* bk = (const float*)d_in[6];
    float* out = (float*)d_out;

    __bf16* big = (__bf16*)d_ws;
    // region A: X (input split) then xq (pass2 output overwrites, X dead)
    __bf16* Ah = big;
    __bf16* Al = big + (size_t)NBIG;
    // region B: head = W2 (dead before pass2), then xk
    __bf16* Bh = big + (size_t)2 * NBIG;
    __bf16* Bl = big + (size_t)3 * NBIG;
    __bf16* W2H = Bh;                 // 640*640
    __bf16* W2L = Bh + WSZ;
    // region C: head = WcT (dead before pass1 writes y2), then y2
    __bf16* Ch = big + (size_t)4 * NBIG;
    __bf16* Cl = big + (size_t)5 * NBIG;
    __bf16* WcTH = Ch;
    __bf16* WcTL = Ch + WSZ;
    // weights + fp32 scratch past the 6 big regions
    __bf16* wp = big + (size_t)6 * NBIG;
    __bf16* WqH = wp;
    __bf16* WqL = wp + WSZ;
    __bf16* WkH = wp + 2 * WSZ;
    __bf16* WkL = wp + 3 * WSZ;
    float* fp = (float*)(wp + 4 * WSZ);
    float* zbias = fp;                    // 640
    float* B2 = fp + 640;                 // 640
    float* bb2 = fp + 1280;               // 1280
    float* gpart = fp + 2560;             // 128000
    float* invb = gpart + 128000;         // 25600
    float* seedsb = invb + 25600;         // 16000
    float* cmb = seedsb + 16000;          // 25600
    float* partb = cmb + 25600;           // 25600
    int* gIdx = (int*)(partb + 25600);    // 25600
    int* gCnt = gIdx + BDIM * HWDIM;      // 25

    const int W4 = WSZ / 4;
    // weight preprocessing
    split_f32<<<dim3((W4 + 255) / 256), 256, 0, stream>>>(Wq, WqH, WqL, W4);
    split_f32<<<dim3((W4 + 255) / 256), 256, 0, stream>>>(Wk, WkH, WkL, W4);
    wtsplit<<<dim3(20, 20), 256, 0, stream>>>(Wc, WcTH, WcTL);   // (Wc+I)^T
    tsplit<<<dim3(32, 20, 25), 256, 0, stream>>>(x5, Ah, Al);    // X
    zero_k<<<1, 640, 0, stream>>>(zbias);
    bias1_k<<<1, 640, 0, stream>>>(Wq, bc, bq, B2);
    hipMemcpyAsync(bb2, bq, CDIM * sizeof(float), hipMemcpyDeviceToDevice, stream);
    hipMemcpyAsync(bb2 + CDIM, bk, CDIM * sizeof(float), hipMemcpyDeviceToDevice,
                   stream);

    // W2 = Wq * (Wc+I): rows from Wq (B-side), cols from WcT (A-side)
    gemm_sm<<<dim3(5, 5, 1), 256, 0, stream>>>(WqH, WqL, WcTH, WcTL, zbias,
                                               W2H, W2L);
    // pass1: y2 = W2 * x + B2
    conv_big<<<dim3(4, 5, 25), 256, 0, stream>>>(Ah, Al, W2H, W2L, W2H, W2L,
                                                 B2, Ch, Cl, Ch, Cl);
    // pass2: xq = Wq*y2 + bq (seg0 -> A), xk = Wk*y2 + bk (seg1 -> B)
    conv_big<<<dim3(4, 10, 25), 256, 0, stream>>>(Ch, Cl, WqH, WqL, WkH, WkL,
                                                  bb2, Ah, Al, Bh, Bl);

    attn_mfma2<<<dim3(40, 5, 5), 256, 0, stream>>>(Ah, Al, Bh, Bl, gpart);
    softmax_mask<<<25, 256, 0, stream>>>(gpart, gIdx, gCnt);
    nrm_k<<<1600, 256, 0, stream>>>(Ch, Cl, invb);
    seeds_k<<<25, 640, 0, stream>>>(Ch, Cl, invb, gIdx, gCnt, seedsb);
    cm_k<<<dim3(256, 5), 256, 0, stream>>>(Ch, Cl, invb, seedsb, cmb);
    minmax_kernel<<<25, 256, 0, stream>>>(cmb);
    proto_part_k<<<dim3(5, 5, 8), 128, 0, stream>>>(Ch, Cl, cmb, partb);
    proto_red_k<<<25, 128, 0, stream>>>(partb, out);
}